// Round 5
// baseline (15936.679 us; speedup 1.0000x reference)
//
#include <hip/hip_runtime.h>
#include <hip/hip_bf16.h>

// BasicLSTM: B=64, T=512, D=512, U=1024.  out = h_last [64][1024] f32.
// Recurrent h exchange flows through L3 via relaxed agent-scope atomics
// (bypass non-coherent per-XCD L2) -- NO release/acquire fences, so no
// per-step buffer_wbl2 / L2-invalidate (round-4's 20 us/step cost).
// Wh stays in VGPRs; zbuf in LDS; xz normal cached loads.

#define T_STEPS 512
#define BATCH   64
#define DIM     512
#define UNITS   1024
#define ZCOLS   4096

typedef float        f32x4 __attribute__((ext_vector_type(4)));
typedef unsigned int u32x4 __attribute__((ext_vector_type(4)));

#define AL(p)    __hip_atomic_load((p), __ATOMIC_RELAXED, __HIP_MEMORY_SCOPE_AGENT)
#define AS(p, v) __hip_atomic_store((p), (v), __ATOMIC_RELAXED, __HIP_MEMORY_SCOPE_AGENT)

union U64x2 { unsigned long long q[2]; u32x4 v; };

__device__ __forceinline__ f32x4 mfma16x16x32_bf16(u32x4 a, u32x4 b, f32x4 c) {
    asm("v_mfma_f32_16x16x32_bf16 %0, %1, %2, %0" : "+v"(c) : "v"(a), "v"(b));
    return c;
}

__device__ __forceinline__ unsigned short f2bf(float f) {
    union { float f; unsigned u; } v; v.f = f;
    unsigned r = v.u + 0x7fffu + ((v.u >> 16) & 1u);   // RNE
    return (unsigned short)(r >> 16);
}

__device__ __forceinline__ float fsigmoid(float x) {
    return 1.0f / (1.0f + __expf(-x));
}
__device__ __forceinline__ float ftanh(float x) {
    return 1.0f - 2.0f / (__expf(2.0f * x) + 1.0f);
}

// pack 8 consecutive f32 -> 8 bf16 in a u32x4 (memory order)
__device__ __forceinline__ u32x4 pack8(const float* __restrict__ p) {
    float4 f0 = reinterpret_cast<const float4*>(p)[0];
    float4 f1 = reinterpret_cast<const float4*>(p)[1];
    u32x4 r;
    r.x = (unsigned)f2bf(f0.x) | ((unsigned)f2bf(f0.y) << 16);
    r.y = (unsigned)f2bf(f0.z) | ((unsigned)f2bf(f0.w) << 16);
    r.z = (unsigned)f2bf(f1.x) | ((unsigned)f2bf(f1.y) << 16);
    r.w = (unsigned)f2bf(f1.z) | ((unsigned)f2bf(f1.w) << 16);
    return r;
}

// ---------------- prep kernels ----------------

// in: f32 [K][N] row-major  ->  out: bf16 [N][K]
__global__ void k_transpose_bf16(const float* __restrict__ in, unsigned short* __restrict__ out,
                                 int K, int N) {
    __shared__ float tile[32][33];
    int n0 = blockIdx.x * 32, k0 = blockIdx.y * 32;
    int tx = threadIdx.x, ty = threadIdx.y;
    tile[ty][tx] = in[(size_t)(k0 + ty) * N + n0 + tx];
    __syncthreads();
    out[(size_t)(n0 + ty) * K + k0 + tx] = f2bf(tile[tx][ty]);
}

__global__ void k_init(unsigned int* __restrict__ hbuf_u32, float* __restrict__ cbuf,
                       unsigned int* __restrict__ flags) {
    int i = blockIdx.x * blockDim.x + threadIdx.x;       // 131072 threads
    if (i < 65536) AS(hbuf_u32 + i, 0u);                 // 2*64*1024 bf16 (L3-visible)
    else cbuf[i - 65536] = 0.0f;                         // 64*1024 f32
    if (i < 2048) AS(flags + i, 0u);                     // 64 flags * 32 u32
}

// ---------------- phase 1: xz(chunk) = x_t @ Wx + b ----------------
// grid (8, T_c), 512 threads = 8 waves. Block: all 64 batch rows x 512 cols
// @ n0 = bx*512, K=512. x packed bf16 -> swizzled LDS once; B from global.
__global__ __launch_bounds__(512, 2) void k_xproj(
        const float* __restrict__ x,
        const unsigned short* __restrict__ WxT,   // [4096][512]
        const float* __restrict__ bias,
        float* __restrict__ xz,                   // [T_c][64][4096]
        int base) {
    const int tid  = threadIdx.x;
    const int lane = tid & 63;
    const int w    = tid >> 6;               // 0..7
    const int n0   = blockIdx.x * 512 + w * 64;
    const int t    = blockIdx.y;
    const int r16  = lane & 15;
    const int kl   = (lane >> 4) * 8;

    __shared__ __align__(16) unsigned short as_[64 * 512];   // 64 KB, XOR-swizzled

    // pack A: x[row, base+t, :] -> bf16 LDS
    for (int i = tid; i < 4096; i += 512) {
        int row = i >> 6, kc = i & 63;
        u32x4 v = pack8(x + ((size_t)row * T_STEPS + base + t) * DIM + kc * 8);
        int lb = (row * 1024 + kc * 16) ^ ((row & 7) << 4);
        *reinterpret_cast<u32x4*>(reinterpret_cast<char*>(as_) + lb) = v;
    }
    __syncthreads();

    const unsigned short* bp = WxT + (size_t)(n0 + r16) * DIM + kl;

    f32x4 acc[4][4] = {};
    asm volatile("s_nop 1" : "+v"(acc[0][0]), "+v"(acc[0][1]), "+v"(acc[0][2]), "+v"(acc[0][3]));
    asm volatile("s_nop 1" : "+v"(acc[1][0]), "+v"(acc[1][1]), "+v"(acc[1][2]), "+v"(acc[1][3]));
    asm volatile("s_nop 1" : "+v"(acc[2][0]), "+v"(acc[2][1]), "+v"(acc[2][2]), "+v"(acc[2][3]));
    asm volatile("s_nop 1" : "+v"(acc[3][0]), "+v"(acc[3][1]), "+v"(acc[3][2]), "+v"(acc[3][3]));

    #pragma unroll 2
    for (int kk = 0; kk < 16; ++kk) {
        u32x4 b0 = *reinterpret_cast<const u32x4*>(bp + kk * 32);
        u32x4 b1 = *reinterpret_cast<const u32x4*>(bp + 16 * DIM + kk * 32);
        u32x4 b2 = *reinterpret_cast<const u32x4*>(bp + 32 * DIM + kk * 32);
        u32x4 b3 = *reinterpret_cast<const u32x4*>(bp + 48 * DIM + kk * 32);
        u32x4 a[4];
        #pragma unroll
        for (int mt = 0; mt < 4; ++mt) {
            int row = mt * 16 + r16;
            int lb = (row * 1024 + (kk * 32 + kl) * 2) ^ ((row & 7) << 4);
            a[mt] = *reinterpret_cast<const u32x4*>(reinterpret_cast<const char*>(as_) + lb);
        }
        #pragma unroll
        for (int mt = 0; mt < 4; ++mt) {
            acc[mt][0] = mfma16x16x32_bf16(a[mt], b0, acc[mt][0]);
            acc[mt][1] = mfma16x16x32_bf16(a[mt], b1, acc[mt][1]);
            acc[mt][2] = mfma16x16x32_bf16(a[mt], b2, acc[mt][2]);
            acc[mt][3] = mfma16x16x32_bf16(a[mt], b3, acc[mt][3]);
        }
    }
    asm volatile("s_nop 7\n\ts_nop 7" : "+v"(acc[0][0]), "+v"(acc[0][1]), "+v"(acc[0][2]), "+v"(acc[0][3]));
    asm volatile("s_nop 7\n\ts_nop 7" : "+v"(acc[1][0]), "+v"(acc[1][1]), "+v"(acc[1][2]), "+v"(acc[1][3]));
    asm volatile("s_nop 7\n\ts_nop 7" : "+v"(acc[2][0]), "+v"(acc[2][1]), "+v"(acc[2][2]), "+v"(acc[2][3]));
    asm volatile("s_nop 7\n\ts_nop 7" : "+v"(acc[3][0]), "+v"(acc[3][1]), "+v"(acc[3][2]), "+v"(acc[3][3]));

    const int rowq = (lane >> 4) * 4;
    #pragma unroll
    for (int nt = 0; nt < 4; ++nt) {
        const int col = n0 + nt * 16 + r16;
        const float bv = bias[col];
        #pragma unroll
        for (int mt = 0; mt < 4; ++mt) {
            #pragma unroll
            for (int r = 0; r < 4; ++r) {
                int brow = mt * 16 + rowq + r;
                xz[((size_t)t * BATCH + brow) * ZCOLS + col] = acc[mt][nt][r] + bv;
            }
        }
    }
}

// ---------------- phase 2: recurrence ----------------
// 64 blocks x 512 threads (8 waves). Block owns 16 units (64 z-cols).
// Wave w: gate ct=w&3, m-half mh=w>>2. Wh column-set in 32 u32x4 VGPRs.
// h exchanged via relaxed agent atomics (L3), no cache fences.
__global__ __launch_bounds__(512, 2) void k_lstm(
        const float* __restrict__ xz,            // [T_c][64][4096], bias folded
        const unsigned short* __restrict__ WhT,  // [4096][1024]
        unsigned short* hbuf,                    // [2][64][1024] bf16
        float* __restrict__ cbuf,                // [64][1024] f32
        float* __restrict__ out,                 // [64][1024] f32
        unsigned int* flags,                     // [64] spaced 32 u32
        int base_step, int tc) {
    const int tid  = threadIdx.x;
    const int lane = tid & 63;
    const int w    = tid >> 6;          // 0..7
    const int ct   = w & 3;             // gate
    const int mh   = w >> 2;            // m half (rows 0-31 / 32-63)
    const int u0   = blockIdx.x * 16;
    const int c16  = lane & 15;
    const int kl   = (lane >> 4) * 8;

    __shared__ float zbuf[64][68];      // ~17 KB

    // B (Wh slice) in registers: col = WhT row ct*1024 + u0 + c16, k window kl
    u32x4 breg[32];
    {
        const unsigned short* wp = WhT + ((size_t)ct * UNITS + u0 + c16) * UNITS + kl;
        #pragma unroll
        for (int kk = 0; kk < 32; ++kk)
            breg[kk] = *reinterpret_cast<const u32x4*>(wp + kk * 32);
    }

    // gate-phase identity: (batch row, unit pair)
    const int row = tid >> 3;            // 0..63
    const int up  = tid & 7;             // 0..7
    const int uc  = u0 + 2 * up;         // even unit col
    float2 cp = *reinterpret_cast<const float2*>(cbuf + (size_t)row * UNITS + uc);

    // u64 base index of this lane's A fragment (row mh*32+c16, k offset kl)
    const size_t aq0 = ((size_t)(mh * 32 + c16) * UNITS + kl) >> 2;

    for (int t = 0; t < tc; ++t) {
        const int s = base_step + t;
        const unsigned long long* hq =
            (const unsigned long long*)(hbuf + (size_t)(s & 1) * (BATCH * UNITS));
        unsigned int* hwq =
            (unsigned int*)(hbuf + (size_t)((s + 1) & 1) * (BATCH * UNITS));

        // prefetch xz for gate phase (normal cached loads, independent of h)
        const float* xp = xz + ((size_t)t * BATCH + row) * ZCOLS + uc;
        float2 x0 = *reinterpret_cast<const float2*>(xp);
        float2 x1 = *reinterpret_cast<const float2*>(xp + UNITS);
        float2 x2 = *reinterpret_cast<const float2*>(xp + 2 * UNITS);
        float2 x3 = *reinterpret_cast<const float2*>(xp + 3 * UNITS);

        // h @ Wh: two m-tiles, K=1024, atomic (L2-bypass) A loads in 4 groups
        f32x4 acc0 = {0, 0, 0, 0}, acc1 = {0, 0, 0, 0};
        asm volatile("s_nop 1" : "+v"(acc0), "+v"(acc1));
        #pragma unroll
        for (int g = 0; g < 4; ++g) {
            U64x2 A0[8], A1[8];
            #pragma unroll
            for (int j = 0; j < 8; ++j) {
                const size_t o = aq0 + (size_t)(g * 8 + j) * 8;
                A0[j].q[0] = AL(hq + o);
                A0[j].q[1] = AL(hq + o + 1);
                A1[j].q[0] = AL(hq + o + 4096);
                A1[j].q[1] = AL(hq + o + 4097);
            }
            #pragma unroll
            for (int j = 0; j < 8; ++j) {
                acc0 = mfma16x16x32_bf16(A0[j].v, breg[g * 8 + j], acc0);
                acc1 = mfma16x16x32_bf16(A1[j].v, breg[g * 8 + j], acc1);
            }
        }
        asm volatile("s_nop 7\n\ts_nop 7" : "+v"(acc0), "+v"(acc1));
        {
            const int rowq = (lane >> 4) * 4;
            #pragma unroll
            for (int r = 0; r < 4; ++r) {
                zbuf[mh * 32 + rowq + r][ct * 16 + c16]      = acc0[r];
                zbuf[mh * 32 + 16 + rowq + r][ct * 16 + c16] = acc1[r];
            }
        }
        __syncthreads();

        // gates: one (row, unit-pair) per thread
        {
            float zi0 = zbuf[row][2 * up]          + x0.x;
            float zi1 = zbuf[row][2 * up + 1]      + x0.y;
            float zf0 = zbuf[row][16 + 2 * up]     + x1.x;
            float zf1 = zbuf[row][16 + 2 * up + 1] + x1.y;
            float zg0 = zbuf[row][32 + 2 * up]     + x2.x;
            float zg1 = zbuf[row][32 + 2 * up + 1] + x2.y;
            float zo0 = zbuf[row][48 + 2 * up]     + x3.x;
            float zo1 = zbuf[row][48 + 2 * up + 1] + x3.y;
            float i0 = fsigmoid(zi0), f0 = fsigmoid(zf0), g0 = ftanh(zg0), o0 = fsigmoid(zo0);
            float i1 = fsigmoid(zi1), f1 = fsigmoid(zf1), g1 = ftanh(zg1), o1 = fsigmoid(zo1);
            cp.x = f0 * cp.x + i0 * g0;
            cp.y = f1 * cp.y + i1 * g1;
            float h0 = o0 * ftanh(cp.x);
            float h1 = o1 * ftanh(cp.y);
            unsigned hp = (unsigned)f2bf(h0) | ((unsigned)f2bf(h1) << 16);
            AS(hwq + (((size_t)row * UNITS + uc) >> 1), hp);
            if (s == T_STEPS - 1) {
                out[(size_t)row * UNITS + uc]     = h0;
                out[(size_t)row * UNITS + uc + 1] = h1;
            }
        }

        // grid barrier (skip on chunk-final step; kernel boundary syncs)
        if (t < tc - 1) {
            asm volatile("s_waitcnt vmcnt(0)" ::: "memory");  // own h stores in L3
            __syncthreads();                                  // whole block drained
            if (w == 0) {
                if (lane == 0)
                    AS(flags + (size_t)blockIdx.x * 32, (unsigned)(s + 1));
                const unsigned tgt = (unsigned)(s + 1);
                for (;;) {
                    unsigned v = AL(flags + (size_t)lane * 32);
                    if (__all((int)(v >= tgt))) break;
                    __builtin_amdgcn_s_sleep(1);
                }
            }
            __syncthreads();
        }
    }
    *reinterpret_cast<float2*>(cbuf + (size_t)row * UNITS + uc) = cp;
}

// ---------------- launch ----------------

extern "C" void kernel_launch(void* const* d_in, const int* in_sizes, int n_in,
                              void* d_out, int out_size, void* d_ws, size_t ws_size,
                              hipStream_t stream) {
    const float* x    = (const float*)d_in[0];   // [64][512][512]
    const float* Wx   = (const float*)d_in[1];   // [512][4096]
    const float* Wh   = (const float*)d_in[2];   // [1024][4096]
    const float* bias = (const float*)d_in[3];   // [4096]

    char* ws = (char*)d_ws;
    unsigned short* WxT   = (unsigned short*)(ws);                            // 4 MB
    unsigned short* WhT   = (unsigned short*)(ws + (4u << 20));               // 8 MB
    unsigned short* hbuf  = (unsigned short*)(ws + (12u << 20));              // 256 KB
    float*          cbuf  = (float*)(ws + (12u << 20) + (256u << 10));        // 256 KB
    unsigned int*   flags = (unsigned int*)(ws + (12u << 20) + (512u << 10)); // 8 KB
    float*          xz    = (float*)(ws + (13u << 20));                       // T_c MB

    // pick largest time-chunk whose xz fits in the remaining workspace
    const size_t fixedB = 13u << 20;
    int tc = 1;
    const int cands[9] = {512, 256, 128, 64, 32, 16, 8, 4, 2};
    for (int i = 0; i < 9; ++i) {
        if (fixedB + (size_t)cands[i] * (1u << 20) <= ws_size) { tc = cands[i]; break; }
    }

    k_transpose_bf16<<<dim3(128, 16), dim3(32, 32), 0, stream>>>(Wx, WxT, 512, 4096);
    k_transpose_bf16<<<dim3(128, 32), dim3(32, 32), 0, stream>>>(Wh, WhT, 1024, 4096);
    k_init<<<512, 256, 0, stream>>>((unsigned int*)hbuf, cbuf, flags);

    const int nch = T_STEPS / tc;
    for (int ci = 0; ci < nch; ++ci) {
        k_xproj<<<dim3(8, tc), 512, 0, stream>>>(x, WxT, bias, xz, ci * tc);
        k_lstm<<<64, 512, 0, stream>>>(xz, WhT, hbuf, cbuf, (float*)d_out, flags,
                                       ci * tc, tc);
    }
}

// Round 8
// 8800.622 us; speedup vs baseline: 1.8109x; 1.8109x over previous
//
#include <hip/hip_runtime.h>
#include <hip/hip_bf16.h>

// BasicLSTM: B=64, T=512, D=512, U=1024.  out = h_last [64][1024] f32.
// Round 8: R4's 64-block structure + fence-free h exchange.
// h / flags cross XCDs via PLAIN inline-asm loads/stores with "sc0 sc1"
// (system scope: bypass L1+L2, serviced at the coherent point / L3).
// -> NO release/acquire, NO wbl2 / L2-invalidate per step (R2/R4's ~14us),
// -> NO __hip_atomic loads (R5's compiler-serialized waitcnt per load).
// A-loads hand-pipelined: 16 in flight, counted vmcnt(8).
// Wh in XOR-swizzled LDS (proven R2). xz/cbuf/out normal cached accesses
// (kernel-boundary coherence).

#define T_STEPS 512
#define BATCH   64
#define DIM     512
#define UNITS   1024
#define ZCOLS   4096

typedef float        f32x4 __attribute__((ext_vector_type(4)));
typedef unsigned int u32x4 __attribute__((ext_vector_type(4)));

__device__ __forceinline__ f32x4 mfma16x16x32_bf16(u32x4 a, u32x4 b, f32x4 c) {
    asm("v_mfma_f32_16x16x32_bf16 %0, %1, %2, %0" : "+v"(c) : "v"(a), "v"(b));
    return c;
}

__device__ __forceinline__ unsigned short f2bf(float f) {
    union { float f; unsigned u; } v; v.f = f;
    unsigned r = v.u + 0x7fffu + ((v.u >> 16) & 1u);   // RNE
    return (unsigned short)(r >> 16);
}

__device__ __forceinline__ float fsigmoid(float x) { return 1.0f / (1.0f + __expf(-x)); }
__device__ __forceinline__ float ftanh(float x)    { return 1.0f - 2.0f / (__expf(2.0f * x) + 1.0f); }

__device__ __forceinline__ u32x4 pack8(const float* __restrict__ p) {
    float4 f0 = reinterpret_cast<const float4*>(p)[0];
    float4 f1 = reinterpret_cast<const float4*>(p)[1];
    u32x4 r;
    r.x = (unsigned)f2bf(f0.x) | ((unsigned)f2bf(f0.y) << 16);
    r.y = (unsigned)f2bf(f0.z) | ((unsigned)f2bf(f0.w) << 16);
    r.z = (unsigned)f2bf(f1.x) | ((unsigned)f2bf(f1.y) << 16);
    r.w = (unsigned)f2bf(f1.z) | ((unsigned)f2bf(f1.w) << 16);
    return r;
}

// ---------------- prep kernels (unchanged, proven R2-R5) ----------------

__global__ void k_transpose_bf16(const float* __restrict__ in, unsigned short* __restrict__ out,
                                 int K, int N) {
    __shared__ float tile[32][33];
    int n0 = blockIdx.x * 32, k0 = blockIdx.y * 32;
    int tx = threadIdx.x, ty = threadIdx.y;
    tile[ty][tx] = in[(size_t)(k0 + ty) * N + n0 + tx];
    __syncthreads();
    out[(size_t)(n0 + ty) * K + k0 + tx] = f2bf(tile[tx][ty]);
}

__global__ void k_init(unsigned int* __restrict__ hbuf_u32, float* __restrict__ cbuf,
                       unsigned int* __restrict__ flags) {
    int i = blockIdx.x * blockDim.x + threadIdx.x;       // 131072 threads
    if (i < 65536) hbuf_u32[i] = 0u;                     // 2*64*1024 bf16
    else cbuf[i - 65536] = 0.0f;                         // 64*1024 f32
    if (i < 2048) flags[i] = 0u;                         // 64 flags * 32 u32
}

// ---------------- phase 1: xz(chunk) = x_t @ Wx + b ----------------
__global__ __launch_bounds__(512, 2) void k_xproj(
        const float* __restrict__ x,
        const unsigned short* __restrict__ WxT,   // [4096][512]
        const float* __restrict__ bias,
        float* __restrict__ xz,                   // [T_c][64][4096]
        int base) {
    const int tid  = threadIdx.x;
    const int lane = tid & 63;
    const int w    = tid >> 6;
    const int n0   = blockIdx.x * 512 + w * 64;
    const int t    = blockIdx.y;
    const int r16  = lane & 15;
    const int kl   = (lane >> 4) * 8;

    __shared__ __align__(16) unsigned short as_[64 * 512];   // 64 KB

    for (int i = tid; i < 4096; i += 512) {
        int row = i >> 6, kc = i & 63;
        u32x4 v = pack8(x + ((size_t)row * T_STEPS + base + t) * DIM + kc * 8);
        int lb = (row * 1024 + kc * 16) ^ ((row & 7) << 4);
        *reinterpret_cast<u32x4*>(reinterpret_cast<char*>(as_) + lb) = v;
    }
    __syncthreads();

    const unsigned short* bp = WxT + (size_t)(n0 + r16) * DIM + kl;

    f32x4 acc[4][4] = {};
    asm volatile("s_nop 1" : "+v"(acc[0][0]), "+v"(acc[1][1]), "+v"(acc[2][2]), "+v"(acc[3][3]));

    #pragma unroll 2
    for (int kk = 0; kk < 16; ++kk) {
        u32x4 b0 = *reinterpret_cast<const u32x4*>(bp + kk * 32);
        u32x4 b1 = *reinterpret_cast<const u32x4*>(bp + 16 * DIM + kk * 32);
        u32x4 b2 = *reinterpret_cast<const u32x4*>(bp + 32 * DIM + kk * 32);
        u32x4 b3 = *reinterpret_cast<const u32x4*>(bp + 48 * DIM + kk * 32);
        u32x4 a[4];
        #pragma unroll
        for (int mt = 0; mt < 4; ++mt) {
            int row = mt * 16 + r16;
            int lb = (row * 1024 + (kk * 32 + kl) * 2) ^ ((row & 7) << 4);
            a[mt] = *reinterpret_cast<const u32x4*>(reinterpret_cast<const char*>(as_) + lb);
        }
        #pragma unroll
        for (int mt = 0; mt < 4; ++mt) {
            acc[mt][0] = mfma16x16x32_bf16(a[mt], b0, acc[mt][0]);
            acc[mt][1] = mfma16x16x32_bf16(a[mt], b1, acc[mt][1]);
            acc[mt][2] = mfma16x16x32_bf16(a[mt], b2, acc[mt][2]);
            acc[mt][3] = mfma16x16x32_bf16(a[mt], b3, acc[mt][3]);
        }
    }
    asm volatile("s_nop 7\n\ts_nop 7" : "+v"(acc[0][0]), "+v"(acc[1][1]), "+v"(acc[2][2]), "+v"(acc[3][3]));

    const int rowq = (lane >> 4) * 4;
    #pragma unroll
    for (int nt = 0; nt < 4; ++nt) {
        const int col = n0 + nt * 16 + r16;
        const float bv = bias[col];
        #pragma unroll
        for (int mt = 0; mt < 4; ++mt)
            #pragma unroll
            for (int r = 0; r < 4; ++r)
                xz[((size_t)t * BATCH + mt * 16 + rowq + r) * ZCOLS + col] = acc[mt][nt][r] + bv;
    }
}

// ---------------- phase 2: recurrence ----------------
// 64 blocks x 512 threads. Block owns 16 units (64 z-cols); Wh slice in
// 128 KB XOR-swizzled LDS. Wave w: gate ct=w&3, m-half mh=w>>2 (two 16-row
// tiles). h via sc0 sc1 asm (L3-coherent), 16 loads in flight, vmcnt(8).

#define LD4(d, base, offs) \
    asm volatile("global_load_dwordx4 %0, %1, off offset:" offs " sc0 sc1" \
                 : "=v"(d) : "v"(base));
#define LDX2(d, base) \
    asm volatile("global_load_dwordx2 %0, %1, off" : "=v"(d) : "v"(base));
#define WAITV(n) \
    asm volatile("s_waitcnt vmcnt(" n ")" ::: "memory"); \
    __builtin_amdgcn_sched_barrier(0);

__global__ __launch_bounds__(512, 2) void k_lstm(
        const float* __restrict__ xz,            // [T_c][64][4096], bias folded
        const unsigned short* __restrict__ WhT,  // [4096][1024]
        unsigned short* hbuf,                    // [2][64][1024] bf16
        float* __restrict__ cbuf,                // [64][1024] f32
        float* __restrict__ out,                 // [64][1024] f32
        unsigned int* flags,                     // [64] spaced 32 u32
        int base_step, int tc) {
    const int tid  = threadIdx.x;
    const int lane = tid & 63;
    const int w    = tid >> 6;          // 0..7
    const int ct   = w & 3;             // gate
    const int mh   = w >> 2;            // m half (rows 0-31 / 32-63)
    const int u0   = blockIdx.x * 16;
    const int c16  = lane & 15;
    const int kl   = (lane >> 4) * 8;   // k offset in elements

    __shared__ __align__(16) unsigned short whs[64 * 1024];  // 128 KB swizzled
    __shared__ float zbuf[64][68];                           // 17 KB

    // stage Wh slice: 64 z-cols (cc = g*16+ui -> WhT row g*1024+u0+ui), k=1024
    for (int i = tid; i < 8192; i += 512) {
        int cc = i >> 7, kc = i & 127;
        int g = cc >> 4, ui = cc & 15;
        u32x4 v = *reinterpret_cast<const u32x4*>(
            WhT + ((size_t)g * UNITS + u0 + ui) * UNITS + kc * 8);
        int lb = (cc * 2048 + kc * 16) ^ ((cc & 7) << 4);
        *reinterpret_cast<u32x4*>(reinterpret_cast<char*>(whs) + lb) = v;
    }

    const int cc_b  = ct * 16 + c16;
    const int bxor  = (cc_b & 7) << 4;
    const char* bptr = reinterpret_cast<const char*>(whs) + cc_b * 2048;
    const int klb   = (lane >> 4) * 16;    // k byte offset within 64B kk-chunk

    // gate identity: (batch row, unit pair)
    const int row = tid >> 3;            // 0..63
    const int up  = tid & 7;             // 0..7
    const int uc  = u0 + 2 * up;
    float2 cp = *reinterpret_cast<const float2*>(cbuf + (size_t)row * UNITS + uc);

    __syncthreads();

    for (int t = 0; t < tc; ++t) {
        const int s = base_step + t;
        const unsigned short* hr = hbuf + (size_t)(s & 1) * (BATCH * UNITS);
        unsigned short*       hw = hbuf + (size_t)((s + 1) & 1) * (BATCH * UNITS);

        // xz prefetch (cached, issued into the vmcnt pipeline first)
        float2 xv0, xv1, xv2, xv3;
        {
            const float* xp = xz + ((size_t)t * BATCH + row) * ZCOLS + uc;
            const float* xp1 = xp + UNITS;
            const float* xp2 = xp + 2 * UNITS;
            const float* xp3 = xp + 3 * UNITS;
            LDX2(xv0, xp) LDX2(xv1, xp1) LDX2(xv2, xp2) LDX2(xv3, xp3)
        }

        // h @ Wh: two m-tiles, K=1024; sc0sc1 loads, 16 in flight
        const unsigned short* a0p = hr + (size_t)(mh * 32 + c16) * UNITS + kl;
        const unsigned short* a1p = a0p + 16 * UNITS;

        f32x4 acc0 = {0, 0, 0, 0}, acc1 = {0, 0, 0, 0};
        asm volatile("s_nop 1" : "+v"(acc0), "+v"(acc1));

        u32x4 A0a[4], A1a[4], A0b[4], A1b[4], B0[4], B1[4];

        #define READB(B, g_) { \
            B[0] = *reinterpret_cast<const u32x4*>(bptr + ((((g_)*4+0)*64 + klb) ^ bxor)); \
            B[1] = *reinterpret_cast<const u32x4*>(bptr + ((((g_)*4+1)*64 + klb) ^ bxor)); \
            B[2] = *reinterpret_cast<const u32x4*>(bptr + ((((g_)*4+2)*64 + klb) ^ bxor)); \
            B[3] = *reinterpret_cast<const u32x4*>(bptr + ((((g_)*4+3)*64 + klb) ^ bxor)); }
        #define ISSUE(S0, S1, O0, O1, O2, O3) \
            LD4(S0[0], a0p, O0) LD4(S0[1], a0p, O1) LD4(S0[2], a0p, O2) LD4(S0[3], a0p, O3) \
            LD4(S1[0], a1p, O0) LD4(S1[1], a1p, O1) LD4(S1[2], a1p, O2) LD4(S1[3], a1p, O3)
        #define CONS(S0, S1, B) \
            acc0 = mfma16x16x32_bf16(S0[0], B[0], acc0); \
            acc1 = mfma16x16x32_bf16(S1[0], B[0], acc1); \
            acc0 = mfma16x16x32_bf16(S0[1], B[1], acc0); \
            acc1 = mfma16x16x32_bf16(S1[1], B[1], acc1); \
            acc0 = mfma16x16x32_bf16(S0[2], B[2], acc0); \
            acc1 = mfma16x16x32_bf16(S1[2], B[2], acc1); \
            acc0 = mfma16x16x32_bf16(S0[3], B[3], acc0); \
            acc1 = mfma16x16x32_bf16(S1[3], B[3], acc1);

        ISSUE(A0a, A1a, "0", "64", "128", "192")          // g0
        ISSUE(A0b, A1b, "256", "320", "384", "448")       // g1
        READB(B0, 0)
        WAITV("8")                                        // xz + g0 done
        READB(B1, 1)  CONS(A0a, A1a, B0)
        ISSUE(A0a, A1a, "512", "576", "640", "704")       // g2
        WAITV("8")                                        // g1 done
        READB(B0, 2)  CONS(A0b, A1b, B1)
        ISSUE(A0b, A1b, "768", "832", "896", "960")       // g3
        WAITV("8")
        READB(B1, 3)  CONS(A0a, A1a, B0)
        ISSUE(A0a, A1a, "1024", "1088", "1152", "1216")   // g4
        WAITV("8")
        READB(B0, 4)  CONS(A0b, A1b, B1)
        ISSUE(A0b, A1b, "1280", "1344", "1408", "1472")   // g5
        WAITV("8")
        READB(B1, 5)  CONS(A0a, A1a, B0)
        ISSUE(A0a, A1a, "1536", "1600", "1664", "1728")   // g6
        WAITV("8")
        READB(B0, 6)  CONS(A0b, A1b, B1)
        ISSUE(A0b, A1b, "1792", "1856", "1920", "1984")   // g7
        WAITV("8")
        READB(B1, 7)  CONS(A0a, A1a, B0)
        WAITV("0")                                        // g7 + xz all done
        CONS(A0b, A1b, B1)

        asm volatile("s_nop 7\n\ts_nop 7" : "+v"(acc0), "+v"(acc1));
        {
            const int rowq = (lane >> 4) * 4;
            #pragma unroll
            for (int r = 0; r < 4; ++r) {
                zbuf[mh * 32 + rowq + r][ct * 16 + c16]      = acc0[r];
                zbuf[mh * 32 + 16 + rowq + r][ct * 16 + c16] = acc1[r];
            }
        }
        __syncthreads();

        // gates: one (row, unit-pair) per thread; h store sc0 sc1 (to L3)
        {
            float zi0 = zbuf[row][2 * up]          + xv0.x;
            float zi1 = zbuf[row][2 * up + 1]      + xv0.y;
            float zf0 = zbuf[row][16 + 2 * up]     + xv1.x;
            float zf1 = zbuf[row][16 + 2 * up + 1] + xv1.y;
            float zg0 = zbuf[row][32 + 2 * up]     + xv2.x;
            float zg1 = zbuf[row][32 + 2 * up + 1] + xv2.y;
            float zo0 = zbuf[row][48 + 2 * up]     + xv3.x;
            float zo1 = zbuf[row][48 + 2 * up + 1] + xv3.y;
            float i0 = fsigmoid(zi0), f0 = fsigmoid(zf0), g0 = ftanh(zg0), o0 = fsigmoid(zo0);
            float i1 = fsigmoid(zi1), f1 = fsigmoid(zf1), g1 = ftanh(zg1), o1 = fsigmoid(zo1);
            cp.x = f0 * cp.x + i0 * g0;
            cp.y = f1 * cp.y + i1 * g1;
            float h0 = o0 * ftanh(cp.x);
            float h1 = o1 * ftanh(cp.y);
            unsigned hp = (unsigned)f2bf(h0) | ((unsigned)f2bf(h1) << 16);
            unsigned int* hwp = reinterpret_cast<unsigned int*>(hw + (size_t)row * UNITS + uc);
            asm volatile("global_store_dword %0, %1, off sc0 sc1" :: "v"(hwp), "v"(hp) : "memory");
            if (s == T_STEPS - 1) {
                out[(size_t)row * UNITS + uc]     = h0;
                out[(size_t)row * UNITS + uc + 1] = h1;
            }
        }

        // grid barrier (skip chunk-final step; kernel boundary syncs)
        if (t < tc - 1) {
            asm volatile("s_waitcnt vmcnt(0)" ::: "memory");   // own h at L3
            __syncthreads();                                   // whole block done
            if (w == 0) {
                if (lane == 0) {
                    unsigned fv = (unsigned)(s + 1);
                    unsigned int* mf = flags + (size_t)blockIdx.x * 32;
                    asm volatile("global_store_dword %0, %1, off sc0 sc1"
                                 :: "v"(mf), "v"(fv) : "memory");
                    asm volatile("s_waitcnt vmcnt(0)" ::: "memory");
                }
                const unsigned tgt = (unsigned)(s + 1);
                const unsigned int* fp = flags + (size_t)lane * 32;
                int iter = 0;
                for (;;) {
                    unsigned v;
                    asm volatile("global_load_dword %0, %1, off sc0 sc1\n\ts_waitcnt vmcnt(0)"
                                 : "=v"(v) : "v"(fp) : "memory");
                    if (__all((int)(v >= tgt))) break;
                    if (++iter > (1 << 20)) break;   // fail loud, never hang
                    __builtin_amdgcn_s_sleep(1);
                }
            }
            __syncthreads();
        }
    }
    *reinterpret_cast<float2*>(cbuf + (size_t)row * UNITS + uc) = cp;
}

// ---------------- launch ----------------

extern "C" void kernel_launch(void* const* d_in, const int* in_sizes, int n_in,
                              void* d_out, int out_size, void* d_ws, size_t ws_size,
                              hipStream_t stream) {
    const float* x    = (const float*)d_in[0];   // [64][512][512]
    const float* Wx   = (const float*)d_in[1];   // [512][4096]
    const float* Wh   = (const float*)d_in[2];   // [1024][4096]
    const float* bias = (const float*)d_in[3];   // [4096]

    char* ws = (char*)d_ws;
    unsigned short* WxT   = (unsigned short*)(ws);                            // 4 MB
    unsigned short* WhT   = (unsigned short*)(ws + (4u << 20));               // 8 MB
    unsigned short* hbuf  = (unsigned short*)(ws + (12u << 20));              // 256 KB
    float*          cbuf  = (float*)(ws + (12u << 20) + (256u << 10));        // 256 KB
    unsigned int*   flags = (unsigned int*)(ws + (12u << 20) + (512u << 10)); // 8 KB
    float*          xz    = (float*)(ws + (13u << 20));                       // T_c MB

    const size_t fixedB = 13u << 20;
    int tc = 1;
    const int cands[9] = {512, 256, 128, 64, 32, 16, 8, 4, 2};
    for (int i = 0; i < 9; ++i)
        if (fixedB + (size_t)cands[i] * (1u << 20) <= ws_size) { tc = cands[i]; break; }

    k_transpose_bf16<<<dim3(128, 16), dim3(32, 32), 0, stream>>>(Wx, WxT, 512, 4096);
    k_transpose_bf16<<<dim3(128, 32), dim3(32, 32), 0, stream>>>(Wh, WhT, 1024, 4096);
    k_init<<<512, 256, 0, stream>>>((unsigned int*)hbuf, cbuf, flags);

    const int nch = T_STEPS / tc;
    for (int ci = 0; ci < nch; ++ci) {
        k_xproj<<<dim3(8, tc), 512, 0, stream>>>(x, WxT, bias, xz, ci * tc);
        k_lstm<<<64, 512, 0, stream>>>(xz, WhT, hbuf, cbuf, (float*)d_out, flags,
                                       ci * tc, tc);
    }
}

// Round 9
// 1904.929 us; speedup vs baseline: 8.3660x; 4.6199x over previous
//
#include <hip/hip_runtime.h>
#include <hip/hip_bf16.h>

// BasicLSTM: B=64, T=512, D=512, U=1024.  out = h_last [64][1024] f32.
// Round 9: batch-grouped recurrence. Grid = 4 m-groups (16 batch rows) x
// 32 z-blocks (128 z-cols = 32 units x 4 gates). A block only ever needs
// its OWN group's h (16 rows x 1024 = 32 KB/step, staged once into
// XOR-swizzled LDS, shared by all 8 waves -> 16x less fabric traffic than
// R8's 512 KB). Wh slice pinned in VGPRs (128 regs, launch_bounds(512,1)).
// h/flags via sc0 sc1 (L3-coherent, no fences). Group-local 32-way barrier.

#define T_STEPS 512
#define BATCH   64
#define DIM     512
#define UNITS   1024
#define ZCOLS   4096
#define MR      16     // rows per m-group

typedef float        f32x4 __attribute__((ext_vector_type(4)));
typedef unsigned int u32x4 __attribute__((ext_vector_type(4)));

__device__ __forceinline__ f32x4 mfma16x16x32_bf16(u32x4 a, u32x4 b, f32x4 c) {
    asm("v_mfma_f32_16x16x32_bf16 %0, %1, %2, %0" : "+v"(c) : "v"(a), "v"(b));
    return c;
}

__device__ __forceinline__ unsigned short f2bf(float f) {
    union { float f; unsigned u; } v; v.f = f;
    unsigned r = v.u + 0x7fffu + ((v.u >> 16) & 1u);   // RNE
    return (unsigned short)(r >> 16);
}

__device__ __forceinline__ float fsigmoid(float x) { return 1.0f / (1.0f + __expf(-x)); }
__device__ __forceinline__ float ftanh(float x)    { return 1.0f - 2.0f / (__expf(2.0f * x) + 1.0f); }

__device__ __forceinline__ u32x4 pack8(const float* __restrict__ p) {
    float4 f0 = reinterpret_cast<const float4*>(p)[0];
    float4 f1 = reinterpret_cast<const float4*>(p)[1];
    u32x4 r;
    r.x = (unsigned)f2bf(f0.x) | ((unsigned)f2bf(f0.y) << 16);
    r.y = (unsigned)f2bf(f0.z) | ((unsigned)f2bf(f0.w) << 16);
    r.z = (unsigned)f2bf(f1.x) | ((unsigned)f2bf(f1.y) << 16);
    r.w = (unsigned)f2bf(f1.z) | ((unsigned)f2bf(f1.w) << 16);
    return r;
}

#define LD4(d, base) \
    asm volatile("global_load_dwordx4 %0, %1, off sc0 sc1" : "=v"(d) : "v"(base));
#define WAITV0 \
    asm volatile("s_waitcnt vmcnt(0)" ::: "memory"); \
    __builtin_amdgcn_sched_barrier(0);

// ---------------- prep kernels ----------------

__global__ void k_transpose_bf16(const float* __restrict__ in, unsigned short* __restrict__ out,
                                 int K, int N) {
    __shared__ float tile[32][33];
    int n0 = blockIdx.x * 32, k0 = blockIdx.y * 32;
    int tx = threadIdx.x, ty = threadIdx.y;
    tile[ty][tx] = in[(size_t)(k0 + ty) * N + n0 + tx];
    __syncthreads();
    out[(size_t)(n0 + ty) * K + k0 + tx] = f2bf(tile[tx][ty]);
}

__global__ void k_init(unsigned int* __restrict__ hbuf_u32, float* __restrict__ cbuf,
                       unsigned int* __restrict__ flags) {
    int i = blockIdx.x * blockDim.x + threadIdx.x;       // 512*512 threads
    if (i < 65536) hbuf_u32[i] = 0u;                     // 2*64*1024 bf16
    else if (i < 131072) cbuf[i - 65536] = 0.0f;         // 64*1024 f32
    else if (i < 131072 + 4096) flags[i - 131072] = 0u;  // 128 flags * 32 u32
}

// ---------------- phase 1: xz(chunk) = x_t @ Wx + b (proven R8) ----------------
__global__ __launch_bounds__(512, 2) void k_xproj(
        const float* __restrict__ x,
        const unsigned short* __restrict__ WxT,   // [4096][512]
        const float* __restrict__ bias,
        float* __restrict__ xz,                   // [T_c][64][4096]
        int base) {
    const int tid  = threadIdx.x;
    const int lane = tid & 63;
    const int w    = tid >> 6;
    const int n0   = blockIdx.x * 512 + w * 64;
    const int t    = blockIdx.y;
    const int r16  = lane & 15;
    const int kl   = (lane >> 4) * 8;

    __shared__ __align__(16) unsigned short as_[64 * 512];   // 64 KB

    for (int i = tid; i < 4096; i += 512) {
        int row = i >> 6, kc = i & 63;
        u32x4 v = pack8(x + ((size_t)row * T_STEPS + base + t) * DIM + kc * 8);
        int lb = (row * 1024 + kc * 16) ^ ((row & 7) << 4);
        *reinterpret_cast<u32x4*>(reinterpret_cast<char*>(as_) + lb) = v;
    }
    __syncthreads();

    const unsigned short* bp = WxT + (size_t)(n0 + r16) * DIM + kl;

    f32x4 acc[4][4] = {};
    asm volatile("s_nop 1" : "+v"(acc[0][0]), "+v"(acc[1][1]), "+v"(acc[2][2]), "+v"(acc[3][3]));

    #pragma unroll 2
    for (int kk = 0; kk < 16; ++kk) {
        u32x4 b0 = *reinterpret_cast<const u32x4*>(bp + kk * 32);
        u32x4 b1 = *reinterpret_cast<const u32x4*>(bp + 16 * DIM + kk * 32);
        u32x4 b2 = *reinterpret_cast<const u32x4*>(bp + 32 * DIM + kk * 32);
        u32x4 b3 = *reinterpret_cast<const u32x4*>(bp + 48 * DIM + kk * 32);
        u32x4 a[4];
        #pragma unroll
        for (int mt = 0; mt < 4; ++mt) {
            int row = mt * 16 + r16;
            int lb = (row * 1024 + (kk * 32 + kl) * 2) ^ ((row & 7) << 4);
            a[mt] = *reinterpret_cast<const u32x4*>(reinterpret_cast<const char*>(as_) + lb);
        }
        #pragma unroll
        for (int mt = 0; mt < 4; ++mt) {
            acc[mt][0] = mfma16x16x32_bf16(a[mt], b0, acc[mt][0]);
            acc[mt][1] = mfma16x16x32_bf16(a[mt], b1, acc[mt][1]);
            acc[mt][2] = mfma16x16x32_bf16(a[mt], b2, acc[mt][2]);
            acc[mt][3] = mfma16x16x32_bf16(a[mt], b3, acc[mt][3]);
        }
    }
    asm volatile("s_nop 7\n\ts_nop 7" : "+v"(acc[0][0]), "+v"(acc[1][1]), "+v"(acc[2][2]), "+v"(acc[3][3]));

    const int rowq = (lane >> 4) * 4;
    #pragma unroll
    for (int nt = 0; nt < 4; ++nt) {
        const int col = n0 + nt * 16 + r16;
        const float bv = bias[col];
        #pragma unroll
        for (int mt = 0; mt < 4; ++mt)
            #pragma unroll
            for (int r = 0; r < 4; ++r)
                xz[((size_t)t * BATCH + mt * 16 + rowq + r) * ZCOLS + col] = acc[mt][nt][r] + bv;
    }
}

// ---------------- phase 2: batch-grouped recurrence ----------------
// 128 blocks x 512 thr. Block (mg = bid>>5, zb = bid&31): rows [16mg,16mg+16),
// units [32zb,32zb+32) x 4 gates. Waves (ct = w&3 gate, kh = w>>2 K-half),
// two 16-col B tiles in VGPRs (breg[2][16] = 128 regs, K=512 window).
__global__ __launch_bounds__(512, 1) void k_lstm(
        const float* __restrict__ xz,            // [T_c][64][4096], bias folded
        const unsigned short* __restrict__ WhT,  // [4096][1024]
        unsigned short* hbuf,                    // [2][64][1024] bf16
        float* __restrict__ cbuf,                // [64][1024] f32
        float* __restrict__ out,                 // [64][1024] f32
        unsigned int* flags,                     // [128] spaced 32 u32
        int base_step, int tc) {
    const int tid  = threadIdx.x;
    const int lane = tid & 63;
    const int w    = tid >> 6;          // 0..7
    const int ct   = w & 3;             // gate
    const int kh   = w >> 2;            // K half
    const int mg   = blockIdx.x >> 5;   // m-group 0..3
    const int zb   = blockIdx.x & 31;   // z-block 0..31
    const int r0   = mg * MR;
    const int u0   = zb * 32;
    const int c16  = lane & 15;
    const int klb  = (lane >> 4) * 16;  // k byte offset within 64B kk-chunk

    __shared__ __align__(16) unsigned short hs[MR * 1024];   // 32 KB, swizzled
    __shared__ float zbuf[2][MR][132];                       // 16.5 KB

    // Wh slice in VGPRs: breg[n][kk] = WhT row ct*1024+u0+n*16+c16,
    // k = kh*512 + kk*32 + (lane>>4)*8
    u32x4 breg[2][16];
    #pragma unroll
    for (int n = 0; n < 2; ++n) {
        const unsigned short* wp =
            WhT + ((size_t)(ct * UNITS + u0 + n * 16 + c16)) * UNITS + kh * 512 + (lane >> 4) * 8;
        #pragma unroll
        for (int kk = 0; kk < 16; ++kk) {
            breg[n][kk] = *reinterpret_cast<const u32x4*>(wp + kk * 32);
            asm volatile("" : "+v"(breg[n][kk]));
        }
    }

    // gate identity: one (row, unit) per thread
    const int ri = tid >> 5;            // 0..15
    const int ui = tid & 31;            // 0..31
    float creg = cbuf[(size_t)(r0 + ri) * UNITS + u0 + ui];

    unsigned int* const myflag = flags + (size_t)blockIdx.x * 32;
    const unsigned int* const gflags = flags + (size_t)mg * 32 * 32;

    for (int t = 0; t < tc; ++t) {
        const int s = base_step + t;
        const unsigned short* hrd = hbuf + (size_t)(s & 1) * (BATCH * UNITS);

        // --- stage group h (16 rows x 1024) -> swizzled LDS, sc0 sc1 ---
        {
            u32x4 sv[4];
            #pragma unroll
            for (int j = 0; j < 4; ++j) {
                int i = tid + j * 512;          // 16B-chunk index 0..2047
                int row = i >> 7, kc = i & 127;
                const unsigned short* src = hrd + (size_t)(r0 + row) * UNITS + kc * 8;
                LD4(sv[j], src)
            }
            WAITV0
            #pragma unroll
            for (int j = 0; j < 4; ++j) {
                int i = tid + j * 512;
                int row = i >> 7, kc = i & 127;
                int lb = (row * 2048 + kc * 16) ^ ((row & 7) << 4);
                *reinterpret_cast<u32x4*>(reinterpret_cast<char*>(hs) + lb) = sv[j];
            }
        }
        __syncthreads();

        // xz prefetch (cached; drains during MFMA phase)
        const float* xp = xz + ((size_t)t * BATCH + r0 + ri) * ZCOLS + u0 + ui;
        float xv0 = xp[0], xv1 = xp[UNITS], xv2 = xp[2 * UNITS], xv3 = xp[3 * UNITS];

        // --- MFMA: 16 kk-steps, A from LDS (shared), B from VGPRs ---
        f32x4 acc0 = {0, 0, 0, 0}, acc1 = {0, 0, 0, 0};
        asm volatile("s_nop 1" : "+v"(acc0), "+v"(acc1));
        const char* abase = reinterpret_cast<const char*>(hs);
        const int axor = (c16 & 7) << 4;
        #pragma unroll
        for (int kk = 0; kk < 16; ++kk) {
            int lb = (c16 * 2048 + kh * 1024 + kk * 64 + klb) ^ axor;
            u32x4 a = *reinterpret_cast<const u32x4*>(abase + lb);
            acc0 = mfma16x16x32_bf16(a, breg[0][kk], acc0);
            acc1 = mfma16x16x32_bf16(a, breg[1][kk], acc1);
        }
        asm volatile("s_nop 7\n\ts_nop 7" : "+v"(acc0), "+v"(acc1));
        {
            const int rowq = (lane >> 4) * 4;
            #pragma unroll
            for (int r = 0; r < 4; ++r) {
                zbuf[kh][rowq + r][ct * 32 + c16]      = acc0[r];
                zbuf[kh][rowq + r][ct * 32 + 16 + c16] = acc1[r];
            }
        }
        __syncthreads();

        // --- gates: all 512 threads, one (ri, ui) each ---
        {
            float zi = zbuf[0][ri][ui]      + zbuf[1][ri][ui]      + xv0;
            float zf = zbuf[0][ri][32 + ui] + zbuf[1][ri][32 + ui] + xv1;
            float zg = zbuf[0][ri][64 + ui] + zbuf[1][ri][64 + ui] + xv2;
            float zo = zbuf[0][ri][96 + ui] + zbuf[1][ri][96 + ui] + xv3;
            float ig = fsigmoid(zi), fg = fsigmoid(zf), gg = ftanh(zg), og = fsigmoid(zo);
            creg = fg * creg + ig * gg;
            float hn = og * ftanh(creg);
            unsigned hv = f2bf(hn);
            unsigned short* hwp = hbuf + (size_t)((s + 1) & 1) * (BATCH * UNITS)
                                  + (size_t)(r0 + ri) * UNITS + u0 + ui;
            asm volatile("global_store_short %0, %1, off sc0 sc1" :: "v"(hwp), "v"(hv) : "memory");
            if (s == T_STEPS - 1) out[(size_t)(r0 + ri) * UNITS + u0 + ui] = hn;
        }

        // --- group-local barrier (32 participants; skip chunk-final) ---
        if (t < tc - 1) {
            WAITV0                              // own h at L3
            __syncthreads();                    // whole block drained
            if (tid == 0) {
                unsigned fv = (unsigned)(s + 1);
                asm volatile("global_store_dword %0, %1, off sc0 sc1"
                             :: "v"(myflag), "v"(fv) : "memory");
                asm volatile("s_waitcnt vmcnt(0)" ::: "memory");
            }
            if (w == 0) {
                const unsigned tgt = (unsigned)(s + 1);
                const unsigned int* fp = gflags + (size_t)(lane & 31) * 32;
                int iter = 0;
                for (;;) {
                    unsigned v;
                    asm volatile("global_load_dword %0, %1, off sc0 sc1\n\ts_waitcnt vmcnt(0)"
                                 : "=v"(v) : "v"(fp) : "memory");
                    if (__all((int)(v >= tgt))) break;
                    if (++iter > (1 << 20)) break;   // fail loud, never hang
                    __builtin_amdgcn_s_sleep(1);
                }
            }
            __syncthreads();
        }
    }
    cbuf[(size_t)(r0 + ri) * UNITS + u0 + ui] = creg;
}

// ---------------- launch ----------------

extern "C" void kernel_launch(void* const* d_in, const int* in_sizes, int n_in,
                              void* d_out, int out_size, void* d_ws, size_t ws_size,
                              hipStream_t stream) {
    const float* x    = (const float*)d_in[0];   // [64][512][512]
    const float* Wx   = (const float*)d_in[1];   // [512][4096]
    const float* Wh   = (const float*)d_in[2];   // [1024][4096]
    const float* bias = (const float*)d_in[3];   // [4096]

    char* ws = (char*)d_ws;
    unsigned short* WxT   = (unsigned short*)(ws);                            // 4 MB
    unsigned short* WhT   = (unsigned short*)(ws + (4u << 20));               // 8 MB
    unsigned short* hbuf  = (unsigned short*)(ws + (12u << 20));              // 256 KB
    float*          cbuf  = (float*)(ws + (12u << 20) + (256u << 10));        // 256 KB
    unsigned int*   flags = (unsigned int*)(ws + (12u << 20) + (512u << 10)); // 16 KB
    float*          xz    = (float*)(ws + (13u << 20));                       // T_c MB

    const size_t fixedB = 13u << 20;
    int tc = 1;
    const int cands[9] = {512, 256, 128, 64, 32, 16, 8, 4, 2};
    for (int i = 0; i < 9; ++i)
        if (fixedB + (size_t)cands[i] * (1u << 20) <= ws_size) { tc = cands[i]; break; }

    k_transpose_bf16<<<dim3(128, 16), dim3(32, 32), 0, stream>>>(Wx, WxT, 512, 4096);
    k_transpose_bf16<<<dim3(128, 32), dim3(32, 32), 0, stream>>>(Wh, WhT, 1024, 4096);
    k_init<<<512, 512, 0, stream>>>((unsigned int*)hbuf, cbuf, flags);

    const int nch = T_STEPS / tc;
    for (int ci = 0; ci < nch; ++ci) {
        k_xproj<<<dim3(8, tc), 512, 0, stream>>>(x, WxT, bias, xz, ci * tc);
        k_lstm<<<128, 512, 0, stream>>>(xz, WhT, hbuf, cbuf, (float*)d_out, flags,
                                        ci * tc, tc);
    }
}